// Round 1
// 472.770 us; speedup vs baseline: 1.1169x; 1.1169x over previous
//
#include <hip/hip_runtime.h>
#include <hip/hip_bf16.h>

// GhostLinear: C[M][N] = x[M][K] @ (lut[idx[N][K]] * scale[N])^T
// M = B*S = 8192, N = OUT_F = 4096, K = IN_F = 4096, fp32 in/out.
// R5: 256x256 tile, BK=64, 8 waves, 128 KiB LDS double-buffer, 8-phase
//     schedule with counted s_waitcnt vmcnt(4) (never 0 in loop), raw
//     s_barrier, s_setprio(1) around MFMA clusters, XCD-swizzled blockIdx.
//     Chunk-rotation LDS layout kept from R4 (measured 0 bank conflicts).

#define M_DIM 8192
#define N_DIM 4096
#define K_DIM 4096
#define BM 256
#define BN 256
#define BK 64
#define NKT (K_DIM / BK)   // 64 K-tiles

typedef __bf16 bf16x8 __attribute__((ext_vector_type(8)));
typedef float floatx4 __attribute__((ext_vector_type(4)));
typedef int intx4 __attribute__((ext_vector_type(4)));
typedef unsigned short ushortx8 __attribute__((ext_vector_type(8)));

__device__ __forceinline__ unsigned short f2bf(float f) {
    return __builtin_bit_cast(unsigned short, (__bf16)f);   // RNE fptrunc
}

// Async global->LDS, 16B per lane. LDS dest = wave-uniform base + lane*16.
__device__ __forceinline__ void async_load16(const void* g, void* l) {
    auto gp = reinterpret_cast<const __attribute__((address_space(1))) void*>(
        reinterpret_cast<unsigned long long>(g));
    auto lp = reinterpret_cast<__attribute__((address_space(3))) void*>(
        static_cast<unsigned int>(reinterpret_cast<unsigned long long>(l)));
    __builtin_amdgcn_global_load_lds(gp, lp, 16, 0, 0);
}

// ---------------- fused pre-pass (unchanged from R4) ----------------
// blocks [0, 16384): x fp32 -> bf16 (8 elems/thread)
// blocks [16384, 24576): W = lut[idx]*scale -> bf16 (8 elems/thread)
__global__ __launch_bounds__(256) void prep(const float* __restrict__ x,
                                            unsigned short* __restrict__ xb,
                                            const int* __restrict__ idx,
                                            const float* __restrict__ scale,
                                            const float* __restrict__ lut,
                                            unsigned short* __restrict__ wb) {
    __shared__ float slut[256];
    if (blockIdx.x < 16384) {
        size_t i = ((size_t)blockIdx.x * 256 + threadIdx.x) * 8;
        floatx4 a = __builtin_nontemporal_load((const floatx4*)(x + i));
        floatx4 b = __builtin_nontemporal_load((const floatx4*)(x + i + 4));
        ushortx8 v;
        v[0] = f2bf(a[0]); v[1] = f2bf(a[1]); v[2] = f2bf(a[2]); v[3] = f2bf(a[3]);
        v[4] = f2bf(b[0]); v[5] = f2bf(b[1]); v[6] = f2bf(b[2]); v[7] = f2bf(b[3]);
        *(ushortx8*)(xb + i) = v;
    } else {
        if (threadIdx.x < 256) slut[threadIdx.x] = lut[threadIdx.x];
        __syncthreads();
        size_t i = ((size_t)(blockIdx.x - 16384) * 256 + threadIdx.x) * 8;
        int row = (int)(i >> 12);                       // / K_DIM
        float s = scale[row];
        intx4 i0 = __builtin_nontemporal_load((const intx4*)(idx + i));
        intx4 i1 = __builtin_nontemporal_load((const intx4*)(idx + i + 4));
        ushortx8 v;
        v[0] = f2bf(slut[i0[0]] * s); v[1] = f2bf(slut[i0[1]] * s);
        v[2] = f2bf(slut[i0[2]] * s); v[3] = f2bf(slut[i0[3]] * s);
        v[4] = f2bf(slut[i1[0]] * s); v[5] = f2bf(slut[i1[1]] * s);
        v[6] = f2bf(slut[i1[2]] * s); v[7] = f2bf(slut[i1[3]] * s);
        *(ushortx8*)(wb + i) = v;
    }
}

// ---------------- 256x256 8-phase bf16 MFMA GEMM ----------------
// A[M][K] bf16 row-major, Bw[N][K] bf16 row-major (B^T), C[M][N] fp32.
// LDS row r stores its 8 16B-chunks rotated: LDS chunk j holds global chunk
// (j - r) & 7; reader of global chunk q uses LDS chunk (q + r) & 7.
//
// Staging slots (read-retirement order):
//   A-slot h = rows with bit6 == h  (read-issued: h=0 in Q(0,*) phase, h=1 in Q(1,*))
//   B-slot h = rows with bit5 == h  (read-issued: h=0 in Q(*,0) first phase, h=1 in Q(*,1))
// Per-iteration (tiles T0=2i in buf0, T0+1 in buf1), stage schedule:
//   P1:buf1.A1<-T0+1  P2:buf1.B1<-T0+1  P3:buf0.A0<-T0+2  P4:buf0.B0<-T0+2 +vmcnt(4)
//   P5:buf0.A1<-T0+2  P6:buf0.B1<-T0+2  P7:buf1.A0<-T0+3  P8:buf1.B0<-T0+3 +vmcnt(4)
// Each slot is staged >=1 full phase after its last ds_read-issuing phase's
// end-barrier; vmcnt(4) leaves only the last 2 phases' loads (4/wave) in flight.

#define SBAR() __builtin_amdgcn_sched_barrier(0)
#define BARRIER()                          \
    do {                                   \
        asm volatile("" ::: "memory");     \
        __builtin_amdgcn_s_barrier();      \
        asm volatile("" ::: "memory");     \
    } while (0)
#define VMCNT4() asm volatile("s_waitcnt vmcnt(4)" ::: "memory")

#define MMA(HM, HN, BR)                                                          \
    do {                                                                         \
        __builtin_amdgcn_s_setprio(1);                                           \
        _Pragma("unroll") for (int mt = 0; mt < 4; mt++)                         \
            _Pragma("unroll") for (int nt = 0; nt < 2; nt++)                     \
                _Pragma("unroll") for (int ks = 0; ks < 2; ks++)                 \
                    acc[(HM) * 4 + mt][(HN) * 2 + nt] =                          \
                        __builtin_amdgcn_mfma_f32_16x16x32_bf16(                 \
                            aReg[mt][ks], BR[nt][ks],                            \
                            acc[(HM) * 4 + mt][(HN) * 2 + nt], 0, 0, 0);         \
        __builtin_amdgcn_s_setprio(0);                                           \
    } while (0)

__global__ __launch_bounds__(512, 2) void gemm256(const unsigned short* __restrict__ A,
                                                  const unsigned short* __restrict__ Bw,
                                                  float* __restrict__ C) {
    extern __shared__ unsigned short lds[];
    unsigned short* __restrict__ As = lds;                 // [2][256][64] = 64 KB
    unsigned short* __restrict__ Bs = lds + 2 * BM * BK;   // [2][256][64] = 64 KB

    // XCD-aware bijective swizzle (512 wgs, 512 % 8 == 0)
    const int id = blockIdx.x;
    const int wg = (id & 7) * 64 + (id >> 3);
    const int m0 = (wg >> 4) * BM;     // 32 m-blocks
    const int n0 = (wg & 15) * BN;     // 16 n-blocks

    const int t    = threadIdx.x;
    const int lane = t & 63;
    const int w    = t >> 6;
    const int wm   = w >> 2;           // 0..1
    const int wn   = w & 3;            // 0..3
    const int quad = lane >> 4;
    const int lcol = lane & 15;

    const int sRow = t >> 3;                          // 0..63
    const int gOff = (((t & 7) - sRow) & 7) * 8;      // rotated global chunk (elems)

    floatx4 acc[8][4];
#pragma unroll
    for (int i = 0; i < 8; i++)
#pragma unroll
        for (int j = 0; j < 4; j++) acc[i][j] = (floatx4)0.0f;

    bf16x8 aReg[4][2], b0Reg[2][2], b1Reg[2][2];

    // stage A-slot half: rows c*128 + half*64 + sRow, c = 0,1
    auto stageA = [&](int buf, int half, int kt) {
        const int ko = (kt & (NKT - 1)) * BK + gOff;
#pragma unroll
        for (int c = 0; c < 2; c++) {
            int r = c * 128 + half * 64 + sRow;
            const unsigned short* s = A + (size_t)(m0 + r) * K_DIM + ko;
            unsigned short* d = As + buf * (BM * BK) + r * BK + (t & 7) * 8;
            async_load16(s, d);
        }
    };
    // stage B-slot half: rows with bit5 == half
    auto stageB = [&](int buf, int half, int kt) {
        const int ko = (kt & (NKT - 1)) * BK + gOff;
#pragma unroll
        for (int c = 0; c < 2; c++) {
            int r = c * 128 + ((sRow >> 5) * 64) + half * 32 + (sRow & 31);
            const unsigned short* s = Bw + (size_t)(n0 + r) * K_DIM + ko;
            unsigned short* d = Bs + buf * (BN * BK) + r * BK + (t & 7) * 8;
            async_load16(s, d);
        }
    };

    auto lda = [&](int buf, int hm) {
#pragma unroll
        for (int mt = 0; mt < 4; mt++) {
            int R = wm * 128 + hm * 64 + mt * 16 + lcol;
#pragma unroll
            for (int ks = 0; ks < 2; ks++) {
                int ch = (ks * 4 + quad + R) & 7;
                aReg[mt][ks] = *(const bf16x8*)(As + buf * (BM * BK) + R * BK + ch * 8);
            }
        }
    };
    auto ldb = [&](bf16x8(&bR)[2][2], int buf, int hn) {
#pragma unroll
        for (int nt = 0; nt < 2; nt++) {
            int R = wn * 64 + hn * 32 + nt * 16 + lcol;
#pragma unroll
            for (int ks = 0; ks < 2; ks++) {
                int ch = (ks * 4 + quad + R) & 7;
                bR[nt][ks] = *(const bf16x8*)(Bs + buf * (BN * BK) + R * BK + ch * 8);
            }
        }
    };

    // prologue: buf0 <- tile 0 (full), buf1 <- tile 1 (A0,B0 only; A1,B1 in P1/P2)
    stageA(0, 0, 0); stageB(0, 0, 0);
    stageA(0, 1, 0); stageB(0, 1, 0);
    stageA(1, 0, 1); stageB(1, 0, 1);
    VMCNT4();          // tile0 fully landed; tile1.A0/B0 may be in flight
    BARRIER();
    SBAR();

    for (int i = 0; i < NKT / 2; i++) {
        const int T0 = 2 * i;
        // ---- P1: Q(0,0) on buf0 ----
        lda(0, 0); ldb(b0Reg, 0, 0);
        stageA(1, 1, T0 + 1);
        SBAR(); BARRIER();
        MMA(0, 0, b0Reg);
        SBAR(); BARRIER(); SBAR();
        // ---- P2: Q(0,1) on buf0 ----
        ldb(b1Reg, 0, 1);
        stageB(1, 1, T0 + 1);
        SBAR(); BARRIER();
        MMA(0, 1, b1Reg);
        SBAR(); BARRIER(); SBAR();
        // ---- P3: Q(1,0) on buf0 ----
        lda(0, 1);
        stageA(0, 0, T0 + 2);
        SBAR(); BARRIER();
        MMA(1, 0, b0Reg);
        SBAR(); BARRIER(); SBAR();
        // ---- P4: Q(1,1) on buf0 ----
        stageB(0, 0, T0 + 2);
        SBAR(); BARRIER();
        MMA(1, 1, b1Reg);
        SBAR(); VMCNT4(); BARRIER(); SBAR();
        // ---- P5: Q(0,0) on buf1 ----
        lda(1, 0); ldb(b0Reg, 1, 0);
        stageA(0, 1, T0 + 2);
        SBAR(); BARRIER();
        MMA(0, 0, b0Reg);
        SBAR(); BARRIER(); SBAR();
        // ---- P6: Q(0,1) on buf1 ----
        ldb(b1Reg, 1, 1);
        stageB(0, 1, T0 + 2);
        SBAR(); BARRIER();
        MMA(0, 1, b1Reg);
        SBAR(); BARRIER(); SBAR();
        // ---- P7: Q(1,0) on buf1 ----
        lda(1, 1);
        stageA(1, 0, T0 + 3);
        SBAR(); BARRIER();
        MMA(1, 0, b0Reg);
        SBAR(); BARRIER(); SBAR();
        // ---- P8: Q(1,1) on buf1 ----
        stageB(1, 0, T0 + 3);
        SBAR(); BARRIER();
        MMA(1, 1, b1Reg);
        SBAR(); VMCNT4(); BARRIER(); SBAR();
    }

    // epilogue: C row = m0 + wm*128 + mt*16 + quad*4 + r, col = n0 + wn*64 + nt*16 + lcol
#pragma unroll
    for (int mt = 0; mt < 8; mt++) {
#pragma unroll
        for (int r = 0; r < 4; r++) {
            int row = m0 + wm * 128 + mt * 16 + quad * 4 + r;
            float* cr = C + (size_t)row * N_DIM + n0 + wn * 64 + lcol;
#pragma unroll
            for (int nt = 0; nt < 4; nt++)
                __builtin_nontemporal_store(acc[mt][nt][r], cr + nt * 16);
        }
    }
}

// ---------------- fallback: correct fp32 tiled GEMM (no workspace) ----------------
__global__ __launch_bounds__(256) void gemm_fallback(const float* __restrict__ x,
                                                     const int* __restrict__ idx,
                                                     const float* __restrict__ scale,
                                                     const float* __restrict__ lut,
                                                     float* __restrict__ C) {
    __shared__ float xs[16][17];
    __shared__ float wsm[16][17];
    const int tx = threadIdx.x & 15;
    const int ty = threadIdx.x >> 4;
    const int m = blockIdx.y * 16 + ty;
    const int n = blockIdx.x * 16 + tx;
    float acc = 0.f;
    for (int k0 = 0; k0 < K_DIM; k0 += 16) {
        xs[ty][tx] = x[(size_t)m * K_DIM + k0 + tx];
        int wrow = blockIdx.x * 16 + ty;
        wsm[ty][tx] = lut[idx[(size_t)wrow * K_DIM + k0 + tx]] * scale[wrow];
        __syncthreads();
#pragma unroll
        for (int kk = 0; kk < 16; kk++) acc += xs[ty][kk] * wsm[tx][kk];
        __syncthreads();
    }
    C[(size_t)m * N_DIM + n] = acc;
}

extern "C" void kernel_launch(void* const* d_in, const int* in_sizes, int n_in,
                              void* d_out, int out_size, void* d_ws, size_t ws_size,
                              hipStream_t stream) {
    const float* x     = (const float*)d_in[0];
    const int*   gidx  = (const int*)d_in[1];
    const float* scale = (const float*)d_in[2];
    const float* lut   = (const float*)d_in[3];
    float*       out   = (float*)d_out;

    const size_t needA = (size_t)M_DIM * K_DIM * sizeof(unsigned short); // 64 MB
    const size_t needW = (size_t)N_DIM * K_DIM * sizeof(unsigned short); // 32 MB

    if (ws_size >= needA + needW) {
        static bool s_attr = false;
        if (!s_attr) {
            (void)hipFuncSetAttribute((const void*)gemm256,
                                      hipFuncAttributeMaxDynamicSharedMemorySize,
                                      131072);
            s_attr = true;
        }
        unsigned short* Ab = (unsigned short*)d_ws;
        unsigned short* Wb = Ab + (size_t)M_DIM * K_DIM;
        prep<<<24576, 256, 0, stream>>>(x, Ab, gidx, scale, lut, Wb);
        gemm256<<<(M_DIM / BM) * (N_DIM / BN), 512, 131072, stream>>>(Ab, Wb, out);
    } else {
        dim3 grid(N_DIM / 16, M_DIM / 16);
        gemm_fallback<<<grid, 16 * 16, 0, stream>>>(x, gidx, scale, lut, out);
    }
}